// Round 6
// baseline (501.629 us; speedup 1.0000x reference)
//
#include <hip/hip_runtime.h>
#include <math.h>

#define NF 128
#define HD 8
#define NPG 2000          // nodes per graph
#define EPB 8000          // edges per sort chunk (4 chunks per graph)
#define TILE 64           // nodes per layer-kernel block (32 tiles/graph)
#define TPG 32            // tiles per graph
#define SLOPE 0.01f

__device__ __forceinline__ float lrelu(float v) {
    return v > 0.0f ? v : SLOPE * v;
}

// ---------------------------------------------------------------------------
// K1: t1 = x @ W1a  (N x 128)@(128 x 8), coalesced via LDS staging.
// ---------------------------------------------------------------------------
__global__ __launch_bounds__(256) void k_feat(const float* __restrict__ x,
                                              const float* __restrict__ W1a,
                                              float* __restrict__ t1, int N) {
    __shared__ float tile[64 * 132];   // 33 KiB
    __shared__ float wl[NF * HD];      // 4 KiB

    const int t = threadIdx.x;
    const size_t base = (size_t)blockIdx.x * 64;

    ((float4*)wl)[t] = ((const float4*)W1a)[t];

    const float4* xg = (const float4*)(x + base * NF);
#pragma unroll
    for (int i = 0; i < 8; ++i) {
        int f4 = t + i * 256;
        float4 v = xg[f4];
        int flat = f4 * 4;
        int n = flat >> 7;
        int k = flat & 127;
        *(float4*)(tile + n * 132 + k) = v;
    }
    __syncthreads();

    const int n = t >> 2;
    const int c0 = (t & 3) * 2;
    float acc0 = 0.0f, acc1 = 0.0f;
    const float* row = tile + n * 132;
#pragma unroll
    for (int k4 = 0; k4 < 32; ++k4) {
        float4 r = *(const float4*)(row + k4 * 4);
        int kb = k4 * 4 * HD;
        acc0 += r.x * wl[kb + c0];          acc1 += r.x * wl[kb + c0 + 1];
        acc0 += r.y * wl[kb + HD + c0];     acc1 += r.y * wl[kb + HD + c0 + 1];
        acc0 += r.z * wl[kb + 2*HD + c0];   acc1 += r.z * wl[kb + 2*HD + c0 + 1];
        acc0 += r.w * wl[kb + 3*HD + c0];   acc1 += r.w * wl[kb + 3*HD + c0 + 1];
    }
    *(float2*)(t1 + (base + n) * HD + c0) = make_float2(acc0, acc1);
}

// ---------------------------------------------------------------------------
// K2: per-chunk counting sort, fully in LDS. 256 blocks (4 per graph).
// Count (ds_add_u32) -> block shfl scan -> LDS scatter (ds_add_rtn) ->
// coalesced dump of sorted srcs + row_ptr. Also inits done[] tickets.
// ---------------------------------------------------------------------------
__global__ __launch_bounds__(1024) void k_sort(const int* __restrict__ ei,
                                               int* __restrict__ gcol,
                                               int* __restrict__ rpc,
                                               int* __restrict__ done,
                                               int E) {
    __shared__ int cnt[NPG];      // counts -> cursors (8 KB)
    __shared__ int srt[EPB];      // sorted srcs (32 KB)
    __shared__ int wtot[16], wpre[16];

    const int b = blockIdx.x;     // chunk id
    const int g = b >> 2;
    const int tid = threadIdx.x;
    const int lane = tid & 63;
    const int wv = tid >> 6;
    const int nodeBase = g * NPG;
    const int e0 = b * EPB;

    if (b < 64 && tid == 0) done[b] = 0;

    for (int i = tid; i < NPG; i += 1024) cnt[i] = 0;
    __syncthreads();

    // count pass
    for (int e = e0 + tid; e < e0 + EPB; e += 1024) {
        int dl = ei[E + e] - nodeBase;
        atomicAdd(&cnt[dl], 1);               // native ds_add_u32
    }
    __syncthreads();

    // block-wide exclusive scan; thread t owns pair (2t, 2t+1)
    int c0 = 0, c1 = 0;
    if (tid < 1000) { c0 = cnt[2 * tid]; c1 = cnt[2 * tid + 1]; }
    int s = c0 + c1;
    int isc = s;
#pragma unroll
    for (int d = 1; d < 64; d <<= 1) {
        int o = __shfl_up(isc, d);
        if (lane >= d) isc += o;
    }
    if (lane == 63) wtot[wv] = isc;
    __syncthreads();
    if (wv == 0) {
        int v = (lane < 16) ? wtot[lane] : 0;
        int iv = v;
#pragma unroll
        for (int d = 1; d < 16; d <<= 1) {
            int o = __shfl_up(iv, d);
            if (lane >= d) iv += o;
        }
        if (lane < 16) wpre[lane] = iv - v;
    }
    __syncthreads();
    int excl = isc - s + wpre[wv];

    int* rpb = rpc + (size_t)b * (NPG + 1);
    if (tid < 1000) {
        cnt[2 * tid]     = excl;
        cnt[2 * tid + 1] = excl + c0;
        rpb[2 * tid]     = excl;
        rpb[2 * tid + 1] = excl + c0;
    }
    if (tid == 0) rpb[NPG] = EPB;
    __syncthreads();

    // scatter pass into LDS
    for (int e = e0 + tid; e < e0 + EPB; e += 1024) {
        int src = ei[e];
        int dl = ei[E + e] - nodeBase;
        int pos = atomicAdd(&cnt[dl], 1);     // ds_add_rtn_u32 (native int)
        srt[pos] = src;
    }
    __syncthreads();

    // coalesced dump
    int4* dst4 = (int4*)(gcol + (size_t)b * EPB);
    const int4* s4 = (const int4*)srt;
    for (int i = tid; i < EPB / 4; i += 1024) dst4[i] = s4[i];
}

// ---------------------------------------------------------------------------
// K3: layer 1 fused: wave-coop gather (phase A) + node-parallel MLP (phase B).
// 32 tiles/graph x 64 nodes -> 2048 blocks (8/CU, 32 waves/CU: occupancy fix).
// Phase A: wave handles 4 nodes/round; 16 lanes/node = 4 lanes x 4 chunks.
// ---------------------------------------------------------------------------
__global__ __launch_bounds__(256) void k_layer1(
    const float* __restrict__ t1, const int* __restrict__ rpc,
    const int* __restrict__ gcol, float* __restrict__ u,
    const float* __restrict__ b1a, const float* __restrict__ W1b,
    const float* __restrict__ b1b, const float* __restrict__ W2a)
{
    __shared__ float agg[TILE * HD];  // 2 KB
    __shared__ float wts[144];        // b1a[8] W1b[64] b1b[8] W2a[64]

    const int tid = threadIdx.x;
    const int g = blockIdx.x >> 5;
    const int tile = blockIdx.x & 31;
    const int n0 = tile * TILE;

    if (tid < 144) {
        float v;
        if (tid < 8)       v = b1a[tid];
        else if (tid < 72) v = W1b[tid - 8];
        else if (tid < 80) v = b1b[tid - 72];
        else               v = W2a[tid - 80];
        wts[tid] = v;
    }

    // ---- phase A: gather ----
    const int lane = tid & 63;
    const int wv = tid >> 6;
    const int sub = lane >> 4;           // node within wave-round (0..3)
    const int p = (lane >> 2) & 3;       // chunk
    const int lj = lane & 3;
    const int* rpb  = rpc + (size_t)((g << 2) + p) * (NPG + 1);
    const int* colp = gcol + (size_t)((g << 2) + p) * EPB;

#pragma unroll
    for (int r = 0; r < 4; ++r) {
        int nl = n0 + r * 16 + wv * 4 + sub;
        bool valid = (nl < NPG);
        float a0 = 0, a1 = 0, a2 = 0, a3 = 0, a4 = 0, a5 = 0, a6 = 0, a7 = 0;
        if (valid) {
            int rs = rpb[nl], re = rpb[nl + 1];
            for (int e = rs + lj; e < re; e += 4) {
                int src = colp[e];
                const float* tr = t1 + (size_t)src * HD;
                float4 pa = *(const float4*)tr;
                float4 pb = *(const float4*)(tr + 4);
                a0 += pa.x; a1 += pa.y; a2 += pa.z; a3 += pa.w;
                a4 += pb.x; a5 += pb.y; a6 += pb.z; a7 += pb.w;
            }
        }
#pragma unroll
        for (int off = 1; off <= 8; off <<= 1) {
            a0 += __shfl_xor(a0, off); a1 += __shfl_xor(a1, off);
            a2 += __shfl_xor(a2, off); a3 += __shfl_xor(a3, off);
            a4 += __shfl_xor(a4, off); a5 += __shfl_xor(a5, off);
            a6 += __shfl_xor(a6, off); a7 += __shfl_xor(a7, off);
        }
        if (valid && (lane & 15) == 0) {
            float* ar = agg + (nl - n0) * HD;
            *(float4*)ar       = make_float4(a0, a1, a2, a3);
            *((float4*)ar + 1) = make_float4(a4, a5, a6, a7);
        }
    }
    __syncthreads();

    // ---- phase B: MLP per node ----
    if (tid < TILE && n0 + tid < NPG) {
        int nl = n0 + tid;
        size_t n = (size_t)g * NPG + nl;
        const float* ti = t1 + n * HD;
        float4 aA = *(const float4*)(agg + tid * HD);
        float4 aB = *((const float4*)(agg + tid * HD) + 1);
        float z[HD];
        z[0] = lrelu(ti[0] + aA.x + wts[0]); z[1] = lrelu(ti[1] + aA.y + wts[1]);
        z[2] = lrelu(ti[2] + aA.z + wts[2]); z[3] = lrelu(ti[3] + aA.w + wts[3]);
        z[4] = lrelu(ti[4] + aB.x + wts[4]); z[5] = lrelu(ti[5] + aB.y + wts[5]);
        z[6] = lrelu(ti[6] + aB.z + wts[6]); z[7] = lrelu(ti[7] + aB.w + wts[7]);

        float h[HD];
#pragma unroll
        for (int j = 0; j < HD; ++j) {
            float acc = wts[72 + j];
#pragma unroll
            for (int c = 0; c < HD; ++c) acc += z[c] * wts[8 + c * HD + j];
            h[j] = lrelu(acc);
        }
        float uu[HD];
#pragma unroll
        for (int j = 0; j < HD; ++j) {
            float acc = 0.0f;
#pragma unroll
            for (int c = 0; c < HD; ++c) acc += h[c] * wts[80 + c * HD + j];
            uu[j] = acc;
        }
        float* ur = u + n * HD;
        *(float4*)ur       = make_float4(uu[0], uu[1], uu[2], uu[3]);
        *(float4*)(ur + 4) = make_float4(uu[4], uu[5], uu[6], uu[7]);
    }
}

// ---------------------------------------------------------------------------
// K4: layer 2 fused + readout. Same gather over u; MLP2 + FC1 + FC2 partials;
// ticket: last of 32 tile-blocks per graph finalizes log_softmax -> out.
// ---------------------------------------------------------------------------
__global__ __launch_bounds__(256) void k_layer2fin(
    const float* __restrict__ u, const int* __restrict__ rpc,
    const int* __restrict__ gcol,
    const float* __restrict__ b2a, const float* __restrict__ W2b,
    const float* __restrict__ b2b, const float* __restrict__ Wf1,
    const float* __restrict__ bf1, const float* __restrict__ Wf2,
    const float* __restrict__ bf2, float* __restrict__ bparts,
    int* __restrict__ done, float* __restrict__ out)
{
    __shared__ float agg[TILE * HD];
    __shared__ float wts[89];         // b2a[8] W2b[64] b2b[8] Wf1[8] bf1[1]
    __shared__ float red[8];

    const int tid = threadIdx.x;
    const int g = blockIdx.x >> 5;
    const int tile = blockIdx.x & 31;
    const int n0 = tile * TILE;

    if (tid < 89) {
        float v;
        if (tid < 8)       v = b2a[tid];
        else if (tid < 72) v = W2b[tid - 8];
        else if (tid < 80) v = b2b[tid - 72];
        else if (tid < 88) v = Wf1[tid - 80];
        else               v = bf1[0];
        wts[tid] = v;
    }

    // ---- phase A: gather over u ----
    const int lane = tid & 63;
    const int wv = tid >> 6;
    const int sub = lane >> 4;
    const int p = (lane >> 2) & 3;
    const int lj = lane & 3;
    const int* rpb  = rpc + (size_t)((g << 2) + p) * (NPG + 1);
    const int* colp = gcol + (size_t)((g << 2) + p) * EPB;

#pragma unroll
    for (int r = 0; r < 4; ++r) {
        int nl = n0 + r * 16 + wv * 4 + sub;
        bool valid = (nl < NPG);
        float a0 = 0, a1 = 0, a2 = 0, a3 = 0, a4 = 0, a5 = 0, a6 = 0, a7 = 0;
        if (valid) {
            int rs = rpb[nl], re = rpb[nl + 1];
            for (int e = rs + lj; e < re; e += 4) {
                int src = colp[e];
                const float* urr = u + (size_t)src * HD;
                float4 pa = *(const float4*)urr;
                float4 pb = *(const float4*)(urr + 4);
                a0 += pa.x; a1 += pa.y; a2 += pa.z; a3 += pa.w;
                a4 += pb.x; a5 += pb.y; a6 += pb.z; a7 += pb.w;
            }
        }
#pragma unroll
        for (int off = 1; off <= 8; off <<= 1) {
            a0 += __shfl_xor(a0, off); a1 += __shfl_xor(a1, off);
            a2 += __shfl_xor(a2, off); a3 += __shfl_xor(a3, off);
            a4 += __shfl_xor(a4, off); a5 += __shfl_xor(a5, off);
            a6 += __shfl_xor(a6, off); a7 += __shfl_xor(a7, off);
        }
        if (valid && (lane & 15) == 0) {
            float* ar = agg + (nl - n0) * HD;
            *(float4*)ar       = make_float4(a0, a1, a2, a3);
            *((float4*)ar + 1) = make_float4(a4, a5, a6, a7);
        }
    }
    __syncthreads();

    // ---- phase B: MLP2 + FC1 + FC2 partials ----
    float acc0 = 0.0f, acc1 = 0.0f;
    if (tid < TILE && n0 + tid < NPG) {
        int nl = n0 + tid;
        size_t n = (size_t)g * NPG + nl;
        const float* ui = u + n * HD;
        float4 aA = *(const float4*)(agg + tid * HD);
        float4 aB = *((const float4*)(agg + tid * HD) + 1);
        float z[HD];
        z[0] = lrelu(ui[0] + aA.x + wts[0]); z[1] = lrelu(ui[1] + aA.y + wts[1]);
        z[2] = lrelu(ui[2] + aA.z + wts[2]); z[3] = lrelu(ui[3] + aA.w + wts[3]);
        z[4] = lrelu(ui[4] + aB.x + wts[4]); z[5] = lrelu(ui[5] + aB.y + wts[5]);
        z[6] = lrelu(ui[6] + aB.z + wts[6]); z[7] = lrelu(ui[7] + aB.w + wts[7]);

        float sv = wts[88];
#pragma unroll
        for (int j = 0; j < HD; ++j) {
            float acc = wts[72 + j];
#pragma unroll
            for (int c = 0; c < HD; ++c) acc += z[c] * wts[8 + c * HD + j];
            sv += lrelu(acc) * wts[80 + j];
        }
        float pf = lrelu(sv);
        float2 wf = *(const float2*)(Wf2 + (size_t)nl * 2);
        acc0 = pf * wf.x;
        acc1 = pf * wf.y;
    }

#pragma unroll
    for (int off = 32; off > 0; off >>= 1) {
        acc0 += __shfl_down(acc0, off);
        acc1 += __shfl_down(acc1, off);
    }
    if (lane == 0) { red[wv * 2] = acc0; red[wv * 2 + 1] = acc1; }
    __syncthreads();

    if (tid == 0) {
        float y0 = red[0] + red[2] + red[4] + red[6];
        float y1 = red[1] + red[3] + red[5] + red[7];
        float* bp = bparts + (size_t)(g * TPG + tile) * 2;
        __hip_atomic_store(&bp[0], y0, __ATOMIC_RELEASE, __HIP_MEMORY_SCOPE_AGENT);
        __hip_atomic_store(&bp[1], y1, __ATOMIC_RELEASE, __HIP_MEMORY_SCOPE_AGENT);
        int old = __hip_atomic_fetch_add(&done[g], 1, __ATOMIC_ACQ_REL,
                                         __HIP_MEMORY_SCOPE_AGENT);
        if (old == TPG - 1) {           // last block of this graph
            float t0 = bf2[0], t1v = bf2[1];
#pragma unroll
            for (int b2 = 0; b2 < TPG; ++b2) {
                const float* q = bparts + (size_t)(g * TPG + b2) * 2;
                t0  += __hip_atomic_load(&q[0], __ATOMIC_ACQUIRE,
                                         __HIP_MEMORY_SCOPE_AGENT);
                t1v += __hip_atomic_load(&q[1], __ATOMIC_ACQUIRE,
                                         __HIP_MEMORY_SCOPE_AGENT);
            }
            float m = fmaxf(t0, t1v);
            float lse = m + logf(expf(t0 - m) + expf(t1v - m));
            out[g * 2 + 0] = t0 - lse;
            out[g * 2 + 1] = t1v - lse;
        }
    }
}

// ---------------------------------------------------------------------------
extern "C" void kernel_launch(void* const* d_in, const int* in_sizes, int n_in,
                              void* d_out, int out_size, void* d_ws, size_t ws_size,
                              hipStream_t stream) {
    const float* x   = (const float*)d_in[0];
    const int*   ei  = (const int*)  d_in[1];
    const float* W1a = (const float*)d_in[3];
    const float* b1a = (const float*)d_in[4];
    const float* W1b = (const float*)d_in[5];
    const float* b1b = (const float*)d_in[6];
    const float* W2a = (const float*)d_in[7];
    const float* b2a = (const float*)d_in[8];
    const float* W2b = (const float*)d_in[9];
    const float* b2b = (const float*)d_in[10];
    const float* Wf1 = (const float*)d_in[11];
    const float* bf1 = (const float*)d_in[12];
    const float* Wf2 = (const float*)d_in[13];
    const float* bf2 = (const float*)d_in[14];

    int N   = in_sizes[0] / NF;        // 128000
    int E   = in_sizes[1] / 2;         // 2048000
    int Bn  = N / NPG;                 // 64 graphs
    int NC  = Bn * 4;                  // 256 chunks

    // workspace carve-up
    float* t1     = (float*)d_ws;                        // N*8        4.1 MB
    float* u      = t1 + (size_t)N * HD;                 // N*8        4.1 MB
    int*   gcol   = (int*)(u + (size_t)N * HD);          // E          8.2 MB
    int*   rpc    = gcol + (size_t)E;                    // NC*(NPG+1) 2.0 MB
    int*   done   = rpc + (size_t)NC * (NPG + 1);        // Bn
    float* bparts = (float*)(done + Bn + 16);            // Bn*32*2

    k_feat     <<<N / 64, 256, 0, stream>>>(x, W1a, t1, N);
    k_sort     <<<NC, 1024, 0, stream>>>(ei, gcol, rpc, done, E);
    k_layer1   <<<Bn * TPG, 256, 0, stream>>>(t1, rpc, gcol, u, b1a, W1b, b1b, W2a);
    k_layer2fin<<<Bn * TPG, 256, 0, stream>>>(u, rpc, gcol, b2a, W2b, b2b, Wf1,
                                              bf1, Wf2, bf2, bparts, done,
                                              (float*)d_out);
}

// Round 7
// 187.513 us; speedup vs baseline: 2.6752x; 2.6752x over previous
//
#include <hip/hip_runtime.h>
#include <math.h>

#define NF 128
#define HD 8
#define NPG 2000          // nodes per graph
#define EPB 8000          // edges per sort chunk (4 chunks per graph)
#define TILE 64           // nodes per layer-kernel block (32 tiles/graph)
#define TPG 32            // tiles per graph
#define SLOPE 0.01f

__device__ __forceinline__ float lrelu(float v) {
    return v > 0.0f ? v : SLOPE * v;
}

// ---------------------------------------------------------------------------
// K1: t1 = x @ W1a  (N x 128)@(128 x 8), coalesced via LDS staging.
// ---------------------------------------------------------------------------
__global__ __launch_bounds__(256) void k_feat(const float* __restrict__ x,
                                              const float* __restrict__ W1a,
                                              float* __restrict__ t1, int N) {
    __shared__ float tile[64 * 132];   // 33 KiB
    __shared__ float wl[NF * HD];      // 4 KiB

    const int t = threadIdx.x;
    const size_t base = (size_t)blockIdx.x * 64;

    ((float4*)wl)[t] = ((const float4*)W1a)[t];

    const float4* xg = (const float4*)(x + base * NF);
#pragma unroll
    for (int i = 0; i < 8; ++i) {
        int f4 = t + i * 256;
        float4 v = xg[f4];
        int flat = f4 * 4;
        int n = flat >> 7;
        int k = flat & 127;
        *(float4*)(tile + n * 132 + k) = v;
    }
    __syncthreads();

    const int n = t >> 2;
    const int c0 = (t & 3) * 2;
    float acc0 = 0.0f, acc1 = 0.0f;
    const float* row = tile + n * 132;
#pragma unroll
    for (int k4 = 0; k4 < 32; ++k4) {
        float4 r = *(const float4*)(row + k4 * 4);
        int kb = k4 * 4 * HD;
        acc0 += r.x * wl[kb + c0];          acc1 += r.x * wl[kb + c0 + 1];
        acc0 += r.y * wl[kb + HD + c0];     acc1 += r.y * wl[kb + HD + c0 + 1];
        acc0 += r.z * wl[kb + 2*HD + c0];   acc1 += r.z * wl[kb + 2*HD + c0 + 1];
        acc0 += r.w * wl[kb + 3*HD + c0];   acc1 += r.w * wl[kb + 3*HD + c0 + 1];
    }
    *(float2*)(t1 + (base + n) * HD + c0) = make_float2(acc0, acc1);
}

// ---------------------------------------------------------------------------
// K2: per-chunk counting sort, fully in LDS. 256 blocks (4 per graph).
// Count (ds_add_u32) -> block shfl scan -> LDS scatter (ds_add_rtn) ->
// coalesced dump of sorted srcs + row_ptr.
// ---------------------------------------------------------------------------
__global__ __launch_bounds__(1024) void k_sort(const int* __restrict__ ei,
                                               int* __restrict__ gcol,
                                               int* __restrict__ rpc,
                                               int E) {
    __shared__ int cnt[NPG];      // counts -> cursors (8 KB)
    __shared__ int srt[EPB];      // sorted srcs (32 KB)
    __shared__ int wtot[16], wpre[16];

    const int b = blockIdx.x;     // chunk id
    const int g = b >> 2;
    const int tid = threadIdx.x;
    const int lane = tid & 63;
    const int wv = tid >> 6;
    const int nodeBase = g * NPG;
    const int e0 = b * EPB;

    for (int i = tid; i < NPG; i += 1024) cnt[i] = 0;
    __syncthreads();

    // count pass
    for (int e = e0 + tid; e < e0 + EPB; e += 1024) {
        int dl = ei[E + e] - nodeBase;
        atomicAdd(&cnt[dl], 1);               // native ds_add_u32
    }
    __syncthreads();

    // block-wide exclusive scan; thread t owns pair (2t, 2t+1)
    int c0 = 0, c1 = 0;
    if (tid < 1000) { c0 = cnt[2 * tid]; c1 = cnt[2 * tid + 1]; }
    int s = c0 + c1;
    int isc = s;
#pragma unroll
    for (int d = 1; d < 64; d <<= 1) {
        int o = __shfl_up(isc, d);
        if (lane >= d) isc += o;
    }
    if (lane == 63) wtot[wv] = isc;
    __syncthreads();
    if (wv == 0) {
        int v = (lane < 16) ? wtot[lane] : 0;
        int iv = v;
#pragma unroll
        for (int d = 1; d < 16; d <<= 1) {
            int o = __shfl_up(iv, d);
            if (lane >= d) iv += o;
        }
        if (lane < 16) wpre[lane] = iv - v;
    }
    __syncthreads();
    int excl = isc - s + wpre[wv];

    int* rpb = rpc + (size_t)b * (NPG + 1);
    if (tid < 1000) {
        cnt[2 * tid]     = excl;
        cnt[2 * tid + 1] = excl + c0;
        rpb[2 * tid]     = excl;
        rpb[2 * tid + 1] = excl + c0;
    }
    if (tid == 0) rpb[NPG] = EPB;
    __syncthreads();

    // scatter pass into LDS
    for (int e = e0 + tid; e < e0 + EPB; e += 1024) {
        int src = ei[e];
        int dl = ei[E + e] - nodeBase;
        int pos = atomicAdd(&cnt[dl], 1);     // ds_add_rtn_u32 (native int)
        srt[pos] = src;
    }
    __syncthreads();

    // coalesced dump
    int4* dst4 = (int4*)(gcol + (size_t)b * EPB);
    const int4* s4 = (const int4*)srt;
    for (int i = tid; i < EPB / 4; i += 1024) dst4[i] = s4[i];
}

// ---------------------------------------------------------------------------
// K3: layer 1 fused: wave-coop gather (phase A) + node-parallel MLP (phase B).
// 32 tiles/graph x 64 nodes -> 2048 blocks. No atomics anywhere.
// ---------------------------------------------------------------------------
__global__ __launch_bounds__(256) void k_layer1(
    const float* __restrict__ t1, const int* __restrict__ rpc,
    const int* __restrict__ gcol, float* __restrict__ u,
    const float* __restrict__ b1a, const float* __restrict__ W1b,
    const float* __restrict__ b1b, const float* __restrict__ W2a)
{
    __shared__ float agg[TILE * HD];  // 2 KB
    __shared__ float wts[144];        // b1a[8] W1b[64] b1b[8] W2a[64]

    const int tid = threadIdx.x;
    const int g = blockIdx.x >> 5;
    const int tile = blockIdx.x & 31;
    const int n0 = tile * TILE;

    if (tid < 144) {
        float v;
        if (tid < 8)       v = b1a[tid];
        else if (tid < 72) v = W1b[tid - 8];
        else if (tid < 80) v = b1b[tid - 72];
        else               v = W2a[tid - 80];
        wts[tid] = v;
    }

    // ---- phase A: gather ----
    const int lane = tid & 63;
    const int wv = tid >> 6;
    const int sub = lane >> 4;           // node within wave-round (0..3)
    const int p = (lane >> 2) & 3;       // chunk
    const int lj = lane & 3;
    const int* rpb  = rpc + (size_t)((g << 2) + p) * (NPG + 1);
    const int* colp = gcol + (size_t)((g << 2) + p) * EPB;

#pragma unroll
    for (int r = 0; r < 4; ++r) {
        int nl = n0 + r * 16 + wv * 4 + sub;
        bool valid = (nl < NPG);
        float a0 = 0, a1 = 0, a2 = 0, a3 = 0, a4 = 0, a5 = 0, a6 = 0, a7 = 0;
        if (valid) {
            int rs = rpb[nl], re = rpb[nl + 1];
            for (int e = rs + lj; e < re; e += 4) {
                int src = colp[e];
                const float* tr = t1 + (size_t)src * HD;
                float4 pa = *(const float4*)tr;
                float4 pb = *(const float4*)(tr + 4);
                a0 += pa.x; a1 += pa.y; a2 += pa.z; a3 += pa.w;
                a4 += pb.x; a5 += pb.y; a6 += pb.z; a7 += pb.w;
            }
        }
#pragma unroll
        for (int off = 1; off <= 8; off <<= 1) {
            a0 += __shfl_xor(a0, off); a1 += __shfl_xor(a1, off);
            a2 += __shfl_xor(a2, off); a3 += __shfl_xor(a3, off);
            a4 += __shfl_xor(a4, off); a5 += __shfl_xor(a5, off);
            a6 += __shfl_xor(a6, off); a7 += __shfl_xor(a7, off);
        }
        if (valid && (lane & 15) == 0) {
            float* ar = agg + (nl - n0) * HD;
            *(float4*)ar       = make_float4(a0, a1, a2, a3);
            *((float4*)ar + 1) = make_float4(a4, a5, a6, a7);
        }
    }
    __syncthreads();

    // ---- phase B: MLP per node ----
    if (tid < TILE && n0 + tid < NPG) {
        int nl = n0 + tid;
        size_t n = (size_t)g * NPG + nl;
        const float* ti = t1 + n * HD;
        float4 aA = *(const float4*)(agg + tid * HD);
        float4 aB = *((const float4*)(agg + tid * HD) + 1);
        float z[HD];
        z[0] = lrelu(ti[0] + aA.x + wts[0]); z[1] = lrelu(ti[1] + aA.y + wts[1]);
        z[2] = lrelu(ti[2] + aA.z + wts[2]); z[3] = lrelu(ti[3] + aA.w + wts[3]);
        z[4] = lrelu(ti[4] + aB.x + wts[4]); z[5] = lrelu(ti[5] + aB.y + wts[5]);
        z[6] = lrelu(ti[6] + aB.z + wts[6]); z[7] = lrelu(ti[7] + aB.w + wts[7]);

        float h[HD];
#pragma unroll
        for (int j = 0; j < HD; ++j) {
            float acc = wts[72 + j];
#pragma unroll
            for (int c = 0; c < HD; ++c) acc += z[c] * wts[8 + c * HD + j];
            h[j] = lrelu(acc);
        }
        float uu[HD];
#pragma unroll
        for (int j = 0; j < HD; ++j) {
            float acc = 0.0f;
#pragma unroll
            for (int c = 0; c < HD; ++c) acc += h[c] * wts[80 + c * HD + j];
            uu[j] = acc;
        }
        float* ur = u + n * HD;
        *(float4*)ur       = make_float4(uu[0], uu[1], uu[2], uu[3]);
        *(float4*)(ur + 4) = make_float4(uu[4], uu[5], uu[6], uu[7]);
    }
}

// ---------------------------------------------------------------------------
// K4: layer 2 + MLP2 + FC1 + FC2 tile-partials. PLAIN STORE finale — the
// agent-scope atomic ticket was the R6 regression (per-XCD L2 non-coherence
// makes acquire/release emit L2 writeback/invalidate; 2048 of them serialized
// the memory system). k_fin does the final reduce instead.
// ---------------------------------------------------------------------------
__global__ __launch_bounds__(256) void k_layer2(
    const float* __restrict__ u, const int* __restrict__ rpc,
    const int* __restrict__ gcol,
    const float* __restrict__ b2a, const float* __restrict__ W2b,
    const float* __restrict__ b2b, const float* __restrict__ Wf1,
    const float* __restrict__ bf1, const float* __restrict__ Wf2,
    float* __restrict__ bparts)
{
    __shared__ float agg[TILE * HD];
    __shared__ float wts[89];         // b2a[8] W2b[64] b2b[8] Wf1[8] bf1[1]
    __shared__ float red[8];

    const int tid = threadIdx.x;
    const int g = blockIdx.x >> 5;
    const int tile = blockIdx.x & 31;
    const int n0 = tile * TILE;

    if (tid < 89) {
        float v;
        if (tid < 8)       v = b2a[tid];
        else if (tid < 72) v = W2b[tid - 8];
        else if (tid < 80) v = b2b[tid - 72];
        else if (tid < 88) v = Wf1[tid - 80];
        else               v = bf1[0];
        wts[tid] = v;
    }

    // ---- phase A: gather over u ----
    const int lane = tid & 63;
    const int wv = tid >> 6;
    const int sub = lane >> 4;
    const int p = (lane >> 2) & 3;
    const int lj = lane & 3;
    const int* rpb  = rpc + (size_t)((g << 2) + p) * (NPG + 1);
    const int* colp = gcol + (size_t)((g << 2) + p) * EPB;

#pragma unroll
    for (int r = 0; r < 4; ++r) {
        int nl = n0 + r * 16 + wv * 4 + sub;
        bool valid = (nl < NPG);
        float a0 = 0, a1 = 0, a2 = 0, a3 = 0, a4 = 0, a5 = 0, a6 = 0, a7 = 0;
        if (valid) {
            int rs = rpb[nl], re = rpb[nl + 1];
            for (int e = rs + lj; e < re; e += 4) {
                int src = colp[e];
                const float* urr = u + (size_t)src * HD;
                float4 pa = *(const float4*)urr;
                float4 pb = *(const float4*)(urr + 4);
                a0 += pa.x; a1 += pa.y; a2 += pa.z; a3 += pa.w;
                a4 += pb.x; a5 += pb.y; a6 += pb.z; a7 += pb.w;
            }
        }
#pragma unroll
        for (int off = 1; off <= 8; off <<= 1) {
            a0 += __shfl_xor(a0, off); a1 += __shfl_xor(a1, off);
            a2 += __shfl_xor(a2, off); a3 += __shfl_xor(a3, off);
            a4 += __shfl_xor(a4, off); a5 += __shfl_xor(a5, off);
            a6 += __shfl_xor(a6, off); a7 += __shfl_xor(a7, off);
        }
        if (valid && (lane & 15) == 0) {
            float* ar = agg + (nl - n0) * HD;
            *(float4*)ar       = make_float4(a0, a1, a2, a3);
            *((float4*)ar + 1) = make_float4(a4, a5, a6, a7);
        }
    }
    __syncthreads();

    // ---- phase B: MLP2 + FC1 + FC2 partials ----
    float acc0 = 0.0f, acc1 = 0.0f;
    if (tid < TILE && n0 + tid < NPG) {
        int nl = n0 + tid;
        size_t n = (size_t)g * NPG + nl;
        const float* ui = u + n * HD;
        float4 aA = *(const float4*)(agg + tid * HD);
        float4 aB = *((const float4*)(agg + tid * HD) + 1);
        float z[HD];
        z[0] = lrelu(ui[0] + aA.x + wts[0]); z[1] = lrelu(ui[1] + aA.y + wts[1]);
        z[2] = lrelu(ui[2] + aA.z + wts[2]); z[3] = lrelu(ui[3] + aA.w + wts[3]);
        z[4] = lrelu(ui[4] + aB.x + wts[4]); z[5] = lrelu(ui[5] + aB.y + wts[5]);
        z[6] = lrelu(ui[6] + aB.z + wts[6]); z[7] = lrelu(ui[7] + aB.w + wts[7]);

        float sv = wts[88];
#pragma unroll
        for (int j = 0; j < HD; ++j) {
            float acc = wts[72 + j];
#pragma unroll
            for (int c = 0; c < HD; ++c) acc += z[c] * wts[8 + c * HD + j];
            sv += lrelu(acc) * wts[80 + j];
        }
        float pf = lrelu(sv);
        float2 wf = *(const float2*)(Wf2 + (size_t)nl * 2);
        acc0 = pf * wf.x;
        acc1 = pf * wf.y;
    }

#pragma unroll
    for (int off = 32; off > 0; off >>= 1) {
        acc0 += __shfl_down(acc0, off);
        acc1 += __shfl_down(acc1, off);
    }
    if (lane == 0) { red[wv * 2] = acc0; red[wv * 2 + 1] = acc1; }
    __syncthreads();

    if (tid == 0) {
        float y0 = red[0] + red[2] + red[4] + red[6];
        float y1 = red[1] + red[3] + red[5] + red[7];
        *(float2*)(bparts + (size_t)(g * TPG + tile) * 2) = make_float2(y0, y1);
    }
}

// ---------------------------------------------------------------------------
// K5: finalize — one thread per graph sums 32 tile partials, log_softmax.
// ---------------------------------------------------------------------------
__global__ __launch_bounds__(64) void k_fin(const float* __restrict__ bparts,
                                            const float* __restrict__ bf2,
                                            float* __restrict__ out, int Bn) {
    int g = threadIdx.x;
    if (g >= Bn) return;
    float y0 = bf2[0], y1 = bf2[1];
#pragma unroll
    for (int b = 0; b < TPG; ++b) {
        float2 v = *(const float2*)(bparts + (size_t)(g * TPG + b) * 2);
        y0 += v.x; y1 += v.y;
    }
    float m = fmaxf(y0, y1);
    float lse = m + logf(expf(y0 - m) + expf(y1 - m));
    out[g * 2 + 0] = y0 - lse;
    out[g * 2 + 1] = y1 - lse;
}

// ---------------------------------------------------------------------------
extern "C" void kernel_launch(void* const* d_in, const int* in_sizes, int n_in,
                              void* d_out, int out_size, void* d_ws, size_t ws_size,
                              hipStream_t stream) {
    const float* x   = (const float*)d_in[0];
    const int*   ei  = (const int*)  d_in[1];
    const float* W1a = (const float*)d_in[3];
    const float* b1a = (const float*)d_in[4];
    const float* W1b = (const float*)d_in[5];
    const float* b1b = (const float*)d_in[6];
    const float* W2a = (const float*)d_in[7];
    const float* b2a = (const float*)d_in[8];
    const float* W2b = (const float*)d_in[9];
    const float* b2b = (const float*)d_in[10];
    const float* Wf1 = (const float*)d_in[11];
    const float* bf1 = (const float*)d_in[12];
    const float* Wf2 = (const float*)d_in[13];
    const float* bf2 = (const float*)d_in[14];

    int N   = in_sizes[0] / NF;        // 128000
    int E   = in_sizes[1] / 2;         // 2048000
    int Bn  = N / NPG;                 // 64 graphs
    int NC  = Bn * 4;                  // 256 chunks

    // workspace carve-up
    float* t1     = (float*)d_ws;                        // N*8        4.1 MB
    float* u      = t1 + (size_t)N * HD;                 // N*8        4.1 MB
    int*   gcol   = (int*)(u + (size_t)N * HD);          // E          8.2 MB
    int*   rpc    = gcol + (size_t)E;                    // NC*(NPG+1) 2.0 MB
    float* bparts = (float*)(rpc + (size_t)NC * (NPG + 1) + 16);  // Bn*32*2

    k_feat  <<<N / 64, 256, 0, stream>>>(x, W1a, t1, N);
    k_sort  <<<NC, 1024, 0, stream>>>(ei, gcol, rpc, E);
    k_layer1<<<Bn * TPG, 256, 0, stream>>>(t1, rpc, gcol, u, b1a, W1b, b1b, W2a);
    k_layer2<<<Bn * TPG, 256, 0, stream>>>(u, rpc, gcol, b2a, W2b, b2b, Wf1,
                                           bf1, Wf2, bparts);
    k_fin   <<<1, 64, 0, stream>>>(bparts, bf2, (float*)d_out, Bn);
}